// Round 11
// baseline (130.967 us; speedup 1.0000x reference)
//
#include <hip/hip_runtime.h>
#include <cmath>

constexpr int NOBJ = 256, CNUM = 151, DDIM = 512;
constexpr int NBDD = NOBJ * DDIM;  // 131072

__device__ __forceinline__ float sigf(float x) { return 1.0f / (1.0f + __expf(-x)); }
__device__ __forceinline__ float tanhf_(float x) {
  float e = __expf(-2.0f * fabsf(x));
  float y = (1.0f - e) / (1.0f + e);
  return copysignf(y, x);
}
__device__ __forceinline__ float4 ld4(const float* p) { return *reinterpret_cast<const float4*>(p); }
__device__ __forceinline__ void st4(float* p, float4 v) { *reinterpret_cast<float4*>(p) = v; }

// ---------------------------------------------------------------------------
// k_pre (all independent of the recurrence):
//  [0,768):    U_z = (z<2 ? w3u : 0) - fac*Wsum_z   (fold hu3+fac into weights)
//  [768,800):  Xps[p][k] = colsum partial of X rows 8p..8p+8 (S seed, iter 1)
//  [800,1056): PoX: Po[2+kh] = split-K partials of X*wo[:,512:]^T (hoisted)
// ---------------------------------------------------------------------------
__global__ void __launch_bounds__(256) k_pre(
    const float* __restrict__ mat, const float* __restrict__ w3w,
    const float* __restrict__ w4w, const float* __restrict__ w5w,
    const float* __restrict__ w3u, const float* __restrict__ X,
    const float* __restrict__ wo, float* __restrict__ U,
    float* __restrict__ Hps, float* __restrict__ Po) {
  __shared__ float sA[64 * 16];
  __shared__ float sB[64 * 66];
  const int t = threadIdx.x;
  const int bx = blockIdx.x;
  if (bx < 768) {  // ---- U fold ----
    const float fac = mat[0] * (float)CNUM;
    const int gid = bx * 256 + t;
    const int z = gid >> 16;
    const int r = gid & 65535;
    const int j = r >> 7, k4 = (r & 127) * 4;
    const float* wz = (z == 0) ? w3w : (z == 1) ? w4w : w5w;
    const float4 a = ld4(wz + (size_t)j * 1024 + k4);
    const float4 b = ld4(wz + (size_t)j * 1024 + 512 + k4);
    float4 u = make_float4(-fac * (a.x + b.x), -fac * (a.y + b.y),
                           -fac * (a.z + b.z), -fac * (a.w + b.w));
    if (z < 2) {
      const float4 w3 = ld4(w3u + (size_t)j * DDIM + k4);
      u.x += w3.x; u.y += w3.y; u.z += w3.z; u.w += w3.w;
    }
    st4(U + (size_t)z * (DDIM * DDIM) + (size_t)j * DDIM + k4, u);
    return;
  }
  if (bx < 800) {  // ---- Xps ----
    const int p = bx - 768;
    const int m0 = p * 8;
    const int k2 = t * 2;
    float s0 = 0.f, s1 = 0.f;
#pragma unroll
    for (int r = 0; r < 8; ++r) {
      const float2 v = *reinterpret_cast<const float2*>(X + (m0 + r) * DDIM + k2);
      s0 += v.x; s1 += v.y;
    }
    Hps[p * DDIM + k2] = s0;
    Hps[p * DDIM + k2 + 1] = s1;
    return;
  }
  // ---- PoX GEMM: X * wo[:,512:]^T, split-K=2 ----
  const int bg = bx - 800;
  const int xcd = bg & 7, slot = bg >> 3;
  const int pp = xcd * 2 + (slot >> 4);
  const int mb = slot & 15;
  const int jb = pp >> 1, kh = pp & 1;
  const int m0 = mb * 16, j0 = jb * 64, kb = kh * 256;
  const int lane = t & 63, wv = t >> 6;
  const int m = t >> 4, k4 = (t & 15) * 4;
  const int jr = t >> 2, kf = (t & 3) * 4;
  float4 rav, rbv[4];
  float acc[4] = {0.f, 0.f, 0.f, 0.f};
#define PX_LOAD(c)                                                              \
  {                                                                             \
    rav = ld4(X + (size_t)(m0 + m) * DDIM + kb + (c) * 64 + k4);                \
    const float* bp = wo + (size_t)(j0 + jr) * 1024 + 512 + kb + (c) * 64 + kf; \
    rbv[0] = ld4(bp);      rbv[1] = ld4(bp + 16);                               \
    rbv[2] = ld4(bp + 32); rbv[3] = ld4(bp + 48);                               \
  }
  PX_LOAD(0);
  for (int c = 0; c < 4; ++c) {
    __syncthreads();
    {
      float* da = sA + k4 * 16 + (m ^ ((t & 3) << 2));
      da[0] = rav.x; da[16] = rav.y; da[32] = rav.z; da[48] = rav.w;
      float* db = sB + kf * 66 + jr;
#pragma unroll
      for (int i = 0; i < 4; ++i) {
        db[(i * 16 + 0) * 66] = rbv[i].x;
        db[(i * 16 + 1) * 66] = rbv[i].y;
        db[(i * 16 + 2) * 66] = rbv[i].z;
        db[(i * 16 + 3) * 66] = rbv[i].w;
      }
    }
    __syncthreads();
    if (c < 3) PX_LOAD(c + 1);
    for (int k4o = 0; k4o < 16; ++k4o) {
      const int abase = (k4o * 4) * 16 + ((wv ^ (k4o & 3)) << 2);
#pragma unroll
      for (int u = 0; u < 4; ++u) {
        const int kk = k4o * 4 + u;
        const float b = sB[kk * 66 + lane];
        const float4 a = ld4(sA + abase + u * 16);
        acc[0] = fmaf(a.x, b, acc[0]); acc[1] = fmaf(a.y, b, acc[1]);
        acc[2] = fmaf(a.z, b, acc[2]); acc[3] = fmaf(a.w, b, acc[3]);
      }
    }
  }
#undef PX_LOAD
#pragma unroll
  for (int i = 0; i < 4; ++i)
    Po[(size_t)(2 + kh) * NBDD + (size_t)(m0 + wv * 4 + i) * DDIM + j0 + lane] = acc[i];
}

// ---------------------------------------------------------------------------
// k_G1: P_z[kh] partials of H*U_z^T (z=0,1,2). Tile 16m x 64j x 256k.
// grid: [0,24) vec tail; [24,792) GEMM (XCD-pinned); [792,1396) Wcs tail
// (FIRST LAUNCH ONLY). vec_z[j] = fac*(S.Wsum_z^T)[j] + biases, S from Hps.
// ---------------------------------------------------------------------------
__global__ void __launch_bounds__(256) k_G1(
    const float* __restrict__ Hc, const float* __restrict__ U,
    const float* __restrict__ Hps, const float* __restrict__ w3w,
    const float* __restrict__ w4w, const float* __restrict__ w5w,
    const float* __restrict__ b3w, const float* __restrict__ b3u,
    const float* __restrict__ b4w, const float* __restrict__ b5w,
    const float* __restrict__ b5u, const float* __restrict__ mat,
    const float* __restrict__ wc, float* __restrict__ Wcs,
    float* __restrict__ P, float* __restrict__ vec) {
  __shared__ float sA[64 * 16];
  __shared__ float sB[64 * 66];
  const int t = threadIdx.x;
  const int bx = blockIdx.x;
  if (bx < 24) {  // ---- vec tail: S build + matvec ----
    const float fac = mat[0] * (float)CNUM;
    const int z = bx >> 3, jp = bx & 7, j0 = jp * 64;
    float* S = sA;  // 512 floats
    {
      const int k2 = t * 2;
      float s0 = 0.f, s1 = 0.f;
#pragma unroll
      for (int p = 0; p < 32; ++p) {
        const float2 v = *reinterpret_cast<const float2*>(Hps + p * DDIM + k2);
        s0 += v.x; s1 += v.y;
      }
      S[k2] = s0; S[k2 + 1] = s1;
    }
    __syncthreads();
    const int jl = t >> 2, q = t & 3;
    const int row = j0 + jl;
    const float* wz = (z == 0) ? w3w : (z == 1) ? w4w : w5w;
    const float* base = wz + (size_t)row * 1024 + q * 128;
    float sum = 0.f;
#pragma unroll
    for (int i = 0; i < 32; ++i) {
      const float4 f1 = ld4(base + 4 * i);
      const float4 f2 = ld4(base + 512 + 4 * i);
      const float4 s4 = ld4(S + q * 128 + 4 * i);
      sum = fmaf(f1.x + f2.x, s4.x, sum);
      sum = fmaf(f1.y + f2.y, s4.y, sum);
      sum = fmaf(f1.z + f2.z, s4.z, sum);
      sum = fmaf(f1.w + f2.w, s4.w, sum);
    }
    sum += __shfl_xor(sum, 1, 64);
    sum += __shfl_xor(sum, 2, 64);
    if (q == 0) {
      const float bias = (z == 0) ? (b3w[row] + b3u[row])
                       : (z == 1) ? (b4w[row] + b3u[row])
                                  : (b5w[row] + b5u[row]);
      vec[z * DDIM + row] = fac * sum + bias;
    }
    return;
  }
  if (bx >= 792) {  // ---- Wcs tail (first launch only) ----
    const int bw = bx - 792;
    const int co = bw >> 2, q = bw & 3;
    const int d = q * 128 + (t & 31) * 4;
    const int g = t >> 5;
    const float* row = wc + (size_t)co * (CNUM * DDIM);
    float4 s = make_float4(0.f, 0.f, 0.f, 0.f);
    for (int c = g; c < CNUM; c += 8) {
      const float4 v = ld4(row + c * DDIM + d);
      s.x += v.x; s.y += v.y; s.z += v.z; s.w += v.w;
    }
    float4* red = reinterpret_cast<float4*>(sA);
    red[t] = s;
    __syncthreads();
    if (t < 128) { red[t].x += red[t+128].x; red[t].y += red[t+128].y;
                   red[t].z += red[t+128].z; red[t].w += red[t+128].w; }
    __syncthreads();
    if (t < 64)  { red[t].x += red[t+64].x; red[t].y += red[t+64].y;
                   red[t].z += red[t+64].z; red[t].w += red[t+64].w; }
    __syncthreads();
    if (t < 32) {
      float4 o = red[t];
      o.x += red[t+32].x; o.y += red[t+32].y; o.z += red[t+32].z; o.w += red[t+32].w;
      st4(Wcs + co * DDIM + q * 128 + t * 4, o);
    }
    return;
  }
  // ---- GEMM path ----
  const int bg = bx - 24;
  const int xcd = bg & 7, slot = bg >> 3;          // slot 0..95
  const int pp = xcd * 6 + (slot >> 4);            // 48 panels
  const int mb = slot & 15;
  const int z = pp >> 4, rr = pp & 15;
  const int jb = rr >> 1, kh = rr & 1;
  const int m0 = mb * 16, j0 = jb * 64, kb = kh * 256;
  const float* Bp = U + (size_t)z * (DDIM * DDIM);
  const int lane = t & 63, wv = t >> 6;
  const int m = t >> 4, k4 = (t & 15) * 4;
  const int jr = t >> 2, kf = (t & 3) * 4;
  float4 rav, rbv[4];
  float acc[4] = {0.f, 0.f, 0.f, 0.f};

#define G1_LOAD(c)                                                          \
  {                                                                         \
    rav = ld4(Hc + (size_t)(m0 + m) * DDIM + kb + (c) * 64 + k4);           \
    const float* bp = Bp + (size_t)(j0 + jr) * DDIM + kb + (c) * 64 + kf;   \
    rbv[0] = ld4(bp);      rbv[1] = ld4(bp + 16);                           \
    rbv[2] = ld4(bp + 32); rbv[3] = ld4(bp + 48);                           \
  }

  G1_LOAD(0);
  for (int c = 0; c < 4; ++c) {
    __syncthreads();
    {
      float* da = sA + k4 * 16 + (m ^ ((t & 3) << 2));
      da[0] = rav.x; da[16] = rav.y; da[32] = rav.z; da[48] = rav.w;
      float* db = sB + kf * 66 + jr;
#pragma unroll
      for (int i = 0; i < 4; ++i) {
        db[(i * 16 + 0) * 66] = rbv[i].x;
        db[(i * 16 + 1) * 66] = rbv[i].y;
        db[(i * 16 + 2) * 66] = rbv[i].z;
        db[(i * 16 + 3) * 66] = rbv[i].w;
      }
    }
    __syncthreads();
    if (c < 3) G1_LOAD(c + 1);
    for (int k4o = 0; k4o < 16; ++k4o) {
      const int abase = (k4o * 4) * 16 + ((wv ^ (k4o & 3)) << 2);
#pragma unroll
      for (int u = 0; u < 4; ++u) {
        const int kk = k4o * 4 + u;
        const float b = sB[kk * 66 + lane];
        const float4 a = ld4(sA + abase + u * 16);
        acc[0] = fmaf(a.x, b, acc[0]); acc[1] = fmaf(a.y, b, acc[1]);
        acc[2] = fmaf(a.z, b, acc[2]); acc[3] = fmaf(a.w, b, acc[3]);
      }
    }
  }
#undef G1_LOAD
  float* op = P + (size_t)(z * 2 + kh) * NBDD;
#pragma unroll
  for (int i = 0; i < 4; ++i)
    op[(size_t)(m0 + wv * 4 + i) * DDIM + j0 + lane] = acc[i];
}

// ---------------------------------------------------------------------------
// k_G2 (split-K=4, R8-proven shape): P5[kq] = (rv.H)*w5u^T over k-quarter kq.
// rv = sig(P1a + P1b + vec1[k]) (folded gate). Tile 16m x 64j x 128k;
// grid 512 = 8jb x 4kq x 16mb; XCD-pinned. Same LDS discipline as k_G1.
// ---------------------------------------------------------------------------
__global__ void __launch_bounds__(256) k_G2(
    const float* __restrict__ Hc, const float* __restrict__ P,
    const float* __restrict__ vec, const float* __restrict__ w5u,
    float* __restrict__ P5) {
  __shared__ float sA[64 * 16];
  __shared__ float sB[64 * 66];
  const int t = threadIdx.x;
  const int bx = blockIdx.x;
  const int xcd = bx & 7, slot = bx >> 3;
  const int pp = xcd * 4 + (slot >> 4);
  const int mb = slot & 15;
  const int jb = pp >> 2, kq = pp & 3;
  const int m0 = mb * 16, j0 = jb * 64, kb = kq * 128;
  const int lane = t & 63, wv = t >> 6;
  const float* P1a = P + (size_t)2 * NBDD;
  const float* P1b = P + (size_t)3 * NBDD;
  const int m = t >> 4, k4 = (t & 15) * 4;
  const int jr = t >> 2, kf = (t & 3) * 4;
  float4 rva, rbv[4];
  float acc[4] = {0.f, 0.f, 0.f, 0.f};

#define G2_LOAD(c)                                                            \
  {                                                                           \
    const int kg = kb + (c) * 64 + k4;                                        \
    const int idx = (m0 + m) * DDIM + kg;                                     \
    const float4 pa = ld4(P1a + idx), pb = ld4(P1b + idx);                    \
    const float4 hh = ld4(Hc + idx);                                          \
    const float4 v1 = ld4(vec + DDIM + kg);                                   \
    rva.x = sigf(pa.x + pb.x + v1.x) * hh.x;                                  \
    rva.y = sigf(pa.y + pb.y + v1.y) * hh.y;                                  \
    rva.z = sigf(pa.z + pb.z + v1.z) * hh.z;                                  \
    rva.w = sigf(pa.w + pb.w + v1.w) * hh.w;                                  \
    const float* bp = w5u + (size_t)(j0 + jr) * DDIM + kb + (c) * 64 + kf;    \
    rbv[0] = ld4(bp);      rbv[1] = ld4(bp + 16);                             \
    rbv[2] = ld4(bp + 32); rbv[3] = ld4(bp + 48);                             \
  }

  G2_LOAD(0);
  for (int c = 0; c < 2; ++c) {
    __syncthreads();
    {
      float* da = sA + k4 * 16 + (m ^ ((t & 3) << 2));
      da[0] = rva.x; da[16] = rva.y; da[32] = rva.z; da[48] = rva.w;
      float* db = sB + kf * 66 + jr;
#pragma unroll
      for (int i = 0; i < 4; ++i) {
        db[(i * 16 + 0) * 66] = rbv[i].x;
        db[(i * 16 + 1) * 66] = rbv[i].y;
        db[(i * 16 + 2) * 66] = rbv[i].z;
        db[(i * 16 + 3) * 66] = rbv[i].w;
      }
    }
    __syncthreads();
    if (c < 1) G2_LOAD(1);
    for (int k4o = 0; k4o < 16; ++k4o) {
      const int abase = (k4o * 4) * 16 + ((wv ^ (k4o & 3)) << 2);
#pragma unroll
      for (int u = 0; u < 4; ++u) {
        const int kk = k4o * 4 + u;
        const float b = sB[kk * 66 + lane];
        const float4 a = ld4(sA + abase + u * 16);
        acc[0] = fmaf(a.x, b, acc[0]); acc[1] = fmaf(a.y, b, acc[1]);
        acc[2] = fmaf(a.z, b, acc[2]); acc[3] = fmaf(a.w, b, acc[3]);
      }
    }
  }
#undef G2_LOAD
#pragma unroll
  for (int i = 0; i < 4; ++i)
    P5[(size_t)kq * NBDD + (size_t)(m0 + wv * 4 + i) * DDIM + j0 + lane] = acc[i];
}

// ---------------------------------------------------------------------------
// k_upd: Hn = (1-zv)*Hc + zv*tanh(P2a+P2b+vec2[j]+SumP5), zv = sig(P0a+P0b+
// vec0[j]). grid 512 = 32mb(8 rows) x 16jb(32 cols). Also emits Hps column
// partials (next iteration's S), deterministic.
// ---------------------------------------------------------------------------
__global__ void __launch_bounds__(256) k_upd(
    const float* __restrict__ Hc, const float* __restrict__ P,
    const float* __restrict__ P5, const float* __restrict__ vec,
    float* __restrict__ Hn, float* __restrict__ Hps) {
  __shared__ float sred[4 * 32];
  const int t = threadIdx.x;
  const int mb = blockIdx.x >> 4, jb = blockIdx.x & 15;
  const int m0 = mb * 8, j0 = jb * 32;
  const int r = t >> 5, c = t & 31;
  const int j = j0 + c;
  const int idx = (m0 + r) * DDIM + j;
  const float zv = sigf(P[idx] + P[(size_t)NBDD + idx] + vec[j]);
  const float p5 = P5[idx] + P5[(size_t)NBDD + idx] +
                   P5[(size_t)2 * NBDD + idx] + P5[(size_t)3 * NBDD + idx];
  const float hv = tanhf_(P[(size_t)4 * NBDD + idx] + P[(size_t)5 * NBDD + idx] +
                          vec[2 * DDIM + j] + p5);
  const float hn = (1.f - zv) * Hc[idx] + zv * hv;
  Hn[idx] = hn;
  // column partials over this block's 8 rows (deterministic)
  const float pr = hn + __shfl_xor(hn, 32, 64);
  const int lane = t & 63, wv = t >> 6;
  if (lane < 32) sred[wv * 32 + lane] = pr;
  __syncthreads();
  if (t < 32)
    Hps[mb * DDIM + j0 + t] =
        sred[t] + sred[32 + t] + sred[64 + t] + sred[96 + t];
}

// ---------------------------------------------------------------------------
// k_out (H-half only): Po[kh] partials of H*wo[:, :512]^T.
// Tile 16m x 64j x 256k; grid 256; XCD pinned.
// ---------------------------------------------------------------------------
__global__ void __launch_bounds__(256) k_out(const float* __restrict__ H,
                                             const float* __restrict__ wo,
                                             float* __restrict__ Po) {
  __shared__ float sA[64 * 16];
  __shared__ float sB[64 * 66];
  const int t = threadIdx.x;
  const int bx = blockIdx.x;
  const int xcd = bx & 7, slot = bx >> 3;
  const int pp = xcd * 2 + (slot >> 4);
  const int mb = slot & 15;
  const int jb = pp >> 1, kh = pp & 1;
  const int m0 = mb * 16, j0 = jb * 64, kb = kh * 256;
  const int lane = t & 63, wv = t >> 6;
  const int m = t >> 4, k4 = (t & 15) * 4;
  const int jr = t >> 2, kf = (t & 3) * 4;
  float4 rav, rbv[4];
  float acc[4] = {0.f, 0.f, 0.f, 0.f};

#define KO_LOAD(c)                                                          \
  {                                                                         \
    rav = ld4(H + (size_t)(m0 + m) * DDIM + kb + (c) * 64 + k4);            \
    const float* bp = wo + (size_t)(j0 + jr) * 1024 + kb + (c) * 64 + kf;   \
    rbv[0] = ld4(bp);      rbv[1] = ld4(bp + 16);                           \
    rbv[2] = ld4(bp + 32); rbv[3] = ld4(bp + 48);                           \
  }

  KO_LOAD(0);
  for (int c = 0; c < 4; ++c) {
    __syncthreads();
    {
      float* da = sA + k4 * 16 + (m ^ ((t & 3) << 2));
      da[0] = rav.x; da[16] = rav.y; da[32] = rav.z; da[48] = rav.w;
      float* db = sB + kf * 66 + jr;
#pragma unroll
      for (int i = 0; i < 4; ++i) {
        db[(i * 16 + 0) * 66] = rbv[i].x;
        db[(i * 16 + 1) * 66] = rbv[i].y;
        db[(i * 16 + 2) * 66] = rbv[i].z;
        db[(i * 16 + 3) * 66] = rbv[i].w;
      }
    }
    __syncthreads();
    if (c < 3) KO_LOAD(c + 1);
    for (int k4o = 0; k4o < 16; ++k4o) {
      const int abase = (k4o * 4) * 16 + ((wv ^ (k4o & 3)) << 2);
#pragma unroll
      for (int u = 0; u < 4; ++u) {
        const int kk = k4o * 4 + u;
        const float b = sB[kk * 66 + lane];
        const float4 a = ld4(sA + abase + u * 16);
        acc[0] = fmaf(a.x, b, acc[0]); acc[1] = fmaf(a.y, b, acc[1]);
        acc[2] = fmaf(a.z, b, acc[2]); acc[3] = fmaf(a.w, b, acc[3]);
      }
    }
  }
#undef KO_LOAD
#pragma unroll
  for (int i = 0; i < 4; ++i)
    Po[(size_t)kh * NBDD + (size_t)(m0 + wv * 4 + i) * DDIM + j0 + lane] = acc[i];
}

// ---------------------------------------------------------------------------
// k_obj: out = relu(sum Po + bo) * Wcs^T + bc. Tile 8m x 64j, grid (32,3).
// ---------------------------------------------------------------------------
__global__ void __launch_bounds__(256) k_obj(const float* __restrict__ Po,
                                             const float* __restrict__ bo,
                                             const float* __restrict__ Wcs,
                                             const float* __restrict__ bc,
                                             float* __restrict__ out) {
  __shared__ float sAo[8 * 519];
  __shared__ float sB[64 * 66];
  const int t = threadIdx.x;
  const int m0 = blockIdx.x * 8, j0 = blockIdx.y * 64;
  const int lane = t & 63, wv = t >> 6;
  const int jr = t >> 2, kf = (t & 3) * 4;
  const int co = j0 + jr;
  {
    const int m = t >> 5, ks4 = (t & 31) * 4;
#pragma unroll
    for (int kb2 = 0; kb2 < 4; ++kb2) {
      const int k = kb2 * 128 + ks4;
      const int idx = (m0 + m) * DDIM + k;
      const float4 p0 = ld4(Po + idx);
      const float4 p1 = ld4(Po + (size_t)NBDD + idx);
      const float4 p2 = ld4(Po + (size_t)2 * NBDD + idx);
      const float4 p3 = ld4(Po + (size_t)3 * NBDD + idx);
      const float4 bb = ld4(bo + k);
      float* da = sAo + m * 519 + k;
      da[0] = fmaxf(p0.x + p1.x + p2.x + p3.x + bb.x, 0.f);
      da[1] = fmaxf(p0.y + p1.y + p2.y + p3.y + bb.y, 0.f);
      da[2] = fmaxf(p0.z + p1.z + p2.z + p3.z + bb.z, 0.f);
      da[3] = fmaxf(p0.w + p1.w + p2.w + p3.w + bb.w, 0.f);
    }
  }
  float4 rbv[4];
  float acc[2] = {0.f, 0.f};
#define OB_LOADB(c)                                                         \
  {                                                                         \
    if (co < CNUM) {                                                        \
      const float* bp = Wcs + (size_t)co * DDIM + (c) * 64 + kf;            \
      rbv[0] = ld4(bp);      rbv[1] = ld4(bp + 16);                         \
      rbv[2] = ld4(bp + 32); rbv[3] = ld4(bp + 48);                         \
    } else {                                                                \
      rbv[0] = rbv[1] = rbv[2] = rbv[3] = make_float4(0.f, 0.f, 0.f, 0.f);  \
    }                                                                       \
  }
  OB_LOADB(0);
  for (int c = 0; c < 8; ++c) {
    __syncthreads();
    {
      float* db = sB + kf * 66 + jr;
#pragma unroll
      for (int i = 0; i < 4; ++i) {
        db[(i * 16 + 0) * 66] = rbv[i].x;
        db[(i * 16 + 1) * 66] = rbv[i].y;
        db[(i * 16 + 2) * 66] = rbv[i].z;
        db[(i * 16 + 3) * 66] = rbv[i].w;
      }
    }
    __syncthreads();
    if (c < 7) OB_LOADB(c + 1);
    const float* a0p = sAo + (wv * 2) * 519 + c * 64;
    const float* a1p = a0p + 519;
#pragma unroll 16
    for (int kk = 0; kk < 64; ++kk) {
      const float b = sB[kk * 66 + lane];
      acc[0] = fmaf(a0p[kk], b, acc[0]);
      acc[1] = fmaf(a1p[kk], b, acc[1]);
    }
  }
#undef OB_LOADB
  const int c_ = j0 + lane;
  if (c_ < CNUM) {
    const float bcv = bc[c_];
    out[(m0 + wv * 2 + 0) * CNUM + c_] = acc[0] + bcv;
    out[(m0 + wv * 2 + 1) * CNUM + c_] = acc[1] + bcv;
  }
}

extern "C" void kernel_launch(void* const* d_in, const int* in_sizes, int n_in,
                              void* d_out, int out_size, void* d_ws, size_t ws_size,
                              hipStream_t stream) {
  const float* X = (const float*)d_in[0];
  const float* mat = (const float*)d_in[1];
  const float* w3w = (const float*)d_in[2];
  const float* b3w = (const float*)d_in[3];
  const float* w3u = (const float*)d_in[4];
  const float* b3u = (const float*)d_in[5];
  const float* w4w = (const float*)d_in[6];
  const float* b4w = (const float*)d_in[7];
  // d_in[8], d_in[9] (w4u, b4u) unused — reference reuses w3u/b3u (faithful bug)
  const float* w5w = (const float*)d_in[10];
  const float* b5w = (const float*)d_in[11];
  const float* w5u = (const float*)d_in[12];
  const float* b5u = (const float*)d_in[13];
  const float* wo = (const float*)d_in[14];
  const float* bo = (const float*)d_in[15];
  const float* wc = (const float*)d_in[16];
  const float* bc = (const float*)d_in[17];
  float* out = (float*)d_out;
  float* ws = (float*)d_ws;

  // workspace (floats): ~11.9 MB
  float* U = ws;                  // 3*512*512 = 786432
  float* Wcs = U + 786432;        // 151*512   = 77312
  float* Hps = Wcs + 77312;       // 32*512    = 16384
  float* vec = Hps + 16384;       // 3*512     = 1536
  float* P = vec + 1536;          // 6*131072  = 786432
  float* P5 = P + 786432;         // 4*131072  = 524288
  float* H0 = P5 + 524288;        // 131072
  float* H1 = H0 + 131072;        // 131072
  float* Po = H1 + 131072;        // 4*131072  = 524288

  // pre: U fold + Xps + X-half of the output GEMM (recurrence-independent)
  k_pre<<<1056, 256, 0, stream>>>(mat, w3w, w4w, w5w, w3u, X, wo, U, Hps, Po);

  // iter 1 (Hc = X); Wcs stream (604 tail blocks) co-scheduled with this G1
  k_G1<<<1396, 256, 0, stream>>>(X, U, Hps, w3w, w4w, w5w, b3w, b3u, b4w, b5w, b5u,
                                 mat, wc, Wcs, P, vec);
  k_G2<<<512, 256, 0, stream>>>(X, P, vec, w5u, P5);
  k_upd<<<512, 256, 0, stream>>>(X, P, P5, vec, H0, Hps);
  // iter 2
  k_G1<<<792, 256, 0, stream>>>(H0, U, Hps, w3w, w4w, w5w, b3w, b3u, b4w, b5w, b5u,
                                mat, wc, Wcs, P, vec);
  k_G2<<<512, 256, 0, stream>>>(H0, P, vec, w5u, P5);
  k_upd<<<512, 256, 0, stream>>>(H0, P, P5, vec, H1, Hps);
  // iter 3
  k_G1<<<792, 256, 0, stream>>>(H1, U, Hps, w3w, w4w, w5w, b3w, b3u, b4w, b5w, b5u,
                                mat, wc, Wcs, P, vec);
  k_G2<<<512, 256, 0, stream>>>(H1, P, vec, w5u, P5);
  k_upd<<<512, 256, 0, stream>>>(H1, P, P5, vec, H0, Hps);
  // epilogue
  k_out<<<256, 256, 0, stream>>>(H0, wo, Po);
  k_obj<<<dim3(32, 3), 256, 0, stream>>>(Po, bo, Wcs, bc, out);
}

// Round 12
// 112.475 us; speedup vs baseline: 1.1644x; 1.1644x over previous
//
#include <hip/hip_runtime.h>
#include <cmath>

constexpr int NOBJ = 256, CNUM = 151, DDIM = 512;
constexpr int NG1 = 512;          // G1 GEMM blocks: 4z x 8jb x 2kh x 8mb
constexpr int NB_DD = NOBJ * DDIM;

__device__ __forceinline__ float sigf(float x) { return 1.0f / (1.0f + __expf(-x)); }
__device__ __forceinline__ float tanhf_(float x) {
  float e = __expf(-2.0f * fabsf(x));
  float y = (1.0f - e) / (1.0f + e);
  return copysignf(y, x);
}
__device__ __forceinline__ float4 ld4(const float* p) { return *reinterpret_cast<const float4*>(p); }

// ---------------------------------------------------------------------------
// k_G1 (split-K=2): hwP[kh][z] partials of H*Wsum_z^T (z<3 folded on load) and
// H*w3u^T (+b3u at kh=0). Tile 32m x 64j x 256k. 4 waves; lane=j; 8m/wave.
// XCD pin: xcd=bid&7 owns 8 (z,jb,kh) panels x 8 mb -> panels L2-resident.
// A in LDS [k][32m] XOR-swizzled (col = m ^ 8*((k>>3)&3)): stores 2-way free,
// reads = aligned wave-uniform b128 broadcast. B in LDS [k][66]: 2-way free.
// Epilogue: psumP[kh][z][mb][512] column partials (deterministic).
// Tail blocks (first launch): Wcs[co][d] = sum_c wc[co][c*512+d].
// ---------------------------------------------------------------------------
__global__ void __launch_bounds__(256) k_G1(
    const float* __restrict__ H, const float* __restrict__ w3w,
    const float* __restrict__ w4w, const float* __restrict__ w5w,
    const float* __restrict__ w3u, const float* __restrict__ b3u,
    float* __restrict__ hwP, float* __restrict__ psumP,
    const float* __restrict__ wc, float* __restrict__ Wcs) {
  __shared__ float sA[64 * 32];
  __shared__ float sB[64 * 66];
  const int t = threadIdx.x;
  const int bx = blockIdx.x;
  if (bx >= NG1) {  // ---- fused Wcs tail (first launch only) ----
    const int bw = bx - NG1;
    const int co = bw >> 2, q = bw & 3;
    const int d = q * 128 + (t & 31) * 4;
    const int g = t >> 5;
    const float* row = wc + (size_t)co * (CNUM * DDIM);
    float4 s = make_float4(0.f, 0.f, 0.f, 0.f);
    for (int c = g; c < CNUM; c += 8) {
      const float4 v = ld4(row + c * DDIM + d);
      s.x += v.x; s.y += v.y; s.z += v.z; s.w += v.w;
    }
    float4* red = reinterpret_cast<float4*>(sA);
    red[t] = s;
    __syncthreads();
    if (t < 128) { red[t].x += red[t+128].x; red[t].y += red[t+128].y;
                   red[t].z += red[t+128].z; red[t].w += red[t+128].w; }
    __syncthreads();
    if (t < 64)  { red[t].x += red[t+64].x; red[t].y += red[t+64].y;
                   red[t].z += red[t+64].z; red[t].w += red[t+64].w; }
    __syncthreads();
    if (t < 32) {
      float4 o = red[t];
      o.x += red[t+32].x; o.y += red[t+32].y; o.z += red[t+32].z; o.w += red[t+32].w;
      *reinterpret_cast<float4*>(Wcs + co * DDIM + q * 128 + t * 4) = o;
    }
    return;
  }
  const int xcd = bx & 7, slot = bx >> 3;
  const int pp = xcd * 8 + (slot >> 3);
  const int mb = slot & 7;
  const int z = pp >> 4, jb = (pp >> 1) & 7, kh = pp & 1;
  const int m0 = mb * 32, j0 = jb * 64, ks = kh * 256;
  const float* W = (z == 0) ? w3w : (z == 1) ? w4w : (z == 2) ? w5w : w3u;
  const int lane = t & 63, wv = t >> 6;
  const int am = t >> 3, ak = (t & 7) * 8;   // A: row am (0-31), k ak..ak+7
  const int jr = t >> 2, kf = (t & 3) * 4;   // B: row jr (0-63), 4 k-quads i*16
  float4 ra0, ra1, rb[4], rb2[4];
  float acc[8] = {0.f, 0.f, 0.f, 0.f, 0.f, 0.f, 0.f, 0.f};

#define G1_LOAD(c)                                                        \
  {                                                                       \
    const float* ap = H + (size_t)(m0 + am) * DDIM + ks + (c) * 64 + ak;  \
    ra0 = ld4(ap); ra1 = ld4(ap + 4);                                     \
    if (z < 3) {                                                          \
      const float* bp = W + (size_t)(j0 + jr) * 1024 + ks + (c) * 64 + kf;\
      rb[0] = ld4(bp);        rb[1] = ld4(bp + 16);                       \
      rb[2] = ld4(bp + 32);   rb[3] = ld4(bp + 48);                       \
      rb2[0] = ld4(bp + 512); rb2[1] = ld4(bp + 528);                     \
      rb2[2] = ld4(bp + 544); rb2[3] = ld4(bp + 560);                     \
    } else {                                                              \
      const float* bp = W + (size_t)(j0 + jr) * DDIM + ks + (c) * 64 + kf;\
      rb[0] = ld4(bp);      rb[1] = ld4(bp + 16);                         \
      rb[2] = ld4(bp + 32); rb[3] = ld4(bp + 48);                         \
    }                                                                     \
  }

  G1_LOAD(0);
  for (int c = 0; c < 4; ++c) {
    __syncthreads();
    {  // A store: col = am ^ 8*((k>>3)&3); (k>>3) = t&7 for all 8 elems
      float* da = sA + ak * 32 + (am ^ (((t & 7) & 3) << 3));
      da[0]   = ra0.x; da[32]  = ra0.y; da[64]  = ra0.z; da[96]  = ra0.w;
      da[128] = ra1.x; da[160] = ra1.y; da[192] = ra1.z; da[224] = ra1.w;
      float* db = sB + kf * 66 + jr;
      if (z < 3) {
#pragma unroll
        for (int i = 0; i < 4; ++i) {
          db[(i * 16 + 0) * 66] = rb[i].x + rb2[i].x;
          db[(i * 16 + 1) * 66] = rb[i].y + rb2[i].y;
          db[(i * 16 + 2) * 66] = rb[i].z + rb2[i].z;
          db[(i * 16 + 3) * 66] = rb[i].w + rb2[i].w;
        }
      } else {
#pragma unroll
        for (int i = 0; i < 4; ++i) {
          db[(i * 16 + 0) * 66] = rb[i].x;
          db[(i * 16 + 1) * 66] = rb[i].y;
          db[(i * 16 + 2) * 66] = rb[i].z;
          db[(i * 16 + 3) * 66] = rb[i].w;
        }
      }
    }
    __syncthreads();
    if (c < 3) G1_LOAD(c + 1);  // in flight during compute
    for (int k8 = 0; k8 < 8; ++k8) {
      const int abase = (k8 * 8) * 32 + ((wv ^ (k8 & 3)) << 3);
#pragma unroll
      for (int u = 0; u < 8; ++u) {
        const int kk = k8 * 8 + u;
        const float b = sB[kk * 66 + lane];
        const float4 a0 = ld4(sA + abase + u * 32);
        const float4 a1 = ld4(sA + abase + u * 32 + 4);
        acc[0] = fmaf(a0.x, b, acc[0]); acc[1] = fmaf(a0.y, b, acc[1]);
        acc[2] = fmaf(a0.z, b, acc[2]); acc[3] = fmaf(a0.w, b, acc[3]);
        acc[4] = fmaf(a1.x, b, acc[4]); acc[5] = fmaf(a1.y, b, acc[5]);
        acc[6] = fmaf(a1.z, b, acc[6]); acc[7] = fmaf(a1.w, b, acc[7]);
      }
    }
  }
#undef G1_LOAD
  float* op = hwP + (size_t)(kh * 4 + z) * NB_DD;
  const float bias = (z == 3 && kh == 0) ? b3u[j0 + lane] : 0.f;
#pragma unroll
  for (int i = 0; i < 8; ++i)
    op[(size_t)(m0 + wv * 8 + i) * DDIM + j0 + lane] = acc[i] + bias;
  if (z < 3) {  // deterministic column partials over this block's 32 rows
    float s = acc[0] + acc[1] + acc[2] + acc[3] + acc[4] + acc[5] + acc[6] + acc[7];
    __syncthreads();
    sA[wv * 64 + lane] = s;
    __syncthreads();
    if (t < 64)
      psumP[((kh * 3 + z) * 8 + mb) * 512 + j0 + t] =
          sA[t] + sA[64 + t] + sA[128 + t] + sA[192 + t];
  }
}

// ---------------------------------------------------------------------------
// k_G2 (split-K=4): P5[kq] partial of (rv.H)*w5u^T over k-quarter kq.
// rv = sig(fac*(svh4-hw4)+b4w+hu3), hw4/hu3 summed from the 2 G1 halves.
// Tile 16m x 64j x 128k; grid 512 = 8jb x 4kq x 16mb; XCD pin on (jb,kq).
// A in LDS [k][16m] XOR-swizzled (col = m ^ 4*((k>>2)&3)), b128 uniform reads.
// ---------------------------------------------------------------------------
__global__ void __launch_bounds__(256) k_G2(
    const float* __restrict__ Hc, const float* __restrict__ hwP,
    const float* __restrict__ psumP, const float* __restrict__ mat,
    const float* __restrict__ b4w, const float* __restrict__ w5u,
    float* __restrict__ P5) {
  __shared__ float sA[64 * 16];
  __shared__ float sB[64 * 66];
  __shared__ float sv4s[128];
  const int t = threadIdx.x;
  const int bx = blockIdx.x;
  const int xcd = bx & 7, slot = bx >> 3;
  const int pp = xcd * 4 + (slot >> 4);
  const int mb = slot & 15;
  const int jb = pp >> 2, kq = pp & 3;
  const int m0 = mb * 16, j0 = jb * 64, kb = kq * 128;
  const int lane = t & 63, wv = t >> 6;
  const float fac = mat[0] * (float)CNUM;
  const float* hw4a = hwP + (size_t)1 * NB_DD;
  const float* hw4b = hwP + (size_t)5 * NB_DD;
  const float* hu3a = hwP + (size_t)3 * NB_DD;
  const float* hu3b = hwP + (size_t)7 * NB_DD;

  if (t < 128) {  // svh4 for this k-quarter = sum of 16 psum partials
    const int k = kb + t;
    float s = 0.f;
#pragma unroll
    for (int mt = 0; mt < 8; ++mt)
      s += psumP[(0 * 3 + 1) * 4096 + mt * 512 + k] +
           psumP[(1 * 3 + 1) * 4096 + mt * 512 + k];
    sv4s[t] = s;
  }

  const int m = t >> 4, k4 = (t & 15) * 4;   // A: row m (0-15), 4 k's
  const int jr = t >> 2, kf = (t & 3) * 4;   // B: row jr, 4 k-quads
  float4 rva;
  float4 rbv[4];
  float acc[4] = {0.f, 0.f, 0.f, 0.f};

#define G2_LOADB(c)                                                           \
  {                                                                           \
    const float* bp = w5u + (size_t)(j0 + jr) * DDIM + kb + (c) * 64 + kf;    \
    rbv[0] = ld4(bp);      rbv[1] = ld4(bp + 16);                             \
    rbv[2] = ld4(bp + 32); rbv[3] = ld4(bp + 48);                             \
  }
#define G2_LOADA(c)                                                           \
  {                                                                           \
    const int kg = kb + (c) * 64 + k4;                                        \
    const int idx = (m0 + m) * DDIM + kg;                                     \
    const float4 h4x = ld4(hw4a + idx), h4y = ld4(hw4b + idx);                \
    const float4 u3x = ld4(hu3a + idx), u3y = ld4(hu3b + idx);                \
    const float4 hh = ld4(Hc + idx);                                          \
    const float4 b4 = ld4(b4w + kg);                                          \
    rva.x = h4x.x + h4y.x; rva.y = h4x.y + h4y.y;                             \
    rva.z = h4x.z + h4y.z; rva.w = h4x.w + h4y.w;                             \
    ru3.x = u3x.x + u3y.x; ru3.y = u3x.y + u3y.y;                             \
    ru3.z = u3x.z + u3y.z; ru3.w = u3x.w + u3y.w;                             \
    rhh = hh; rb4 = b4;                                                       \
  }
  float4 ru3, rhh, rb4;

  G2_LOADA(0); G2_LOADB(0);
  for (int c = 0; c < 2; ++c) {
    __syncthreads();
    {  // rv*H store, col = m ^ 4*((k>>2)&3); (k>>2)&3 = (t&15)&3 const
      const int kloc = c * 64 + k4;
      const float4 s4 = ld4(sv4s + kloc);
      float* da = sA + k4 * 16 + (m ^ (((t & 15) & 3) << 2));
      da[0]  = sigf(fac * (s4.x - rva.x) + rb4.x + ru3.x) * rhh.x;
      da[16] = sigf(fac * (s4.y - rva.y) + rb4.y + ru3.y) * rhh.y;
      da[32] = sigf(fac * (s4.z - rva.z) + rb4.z + ru3.z) * rhh.z;
      da[48] = sigf(fac * (s4.w - rva.w) + rb4.w + ru3.w) * rhh.w;
      float* db = sB + kf * 66 + jr;
#pragma unroll
      for (int i = 0; i < 4; ++i) {
        db[(i * 16 + 0) * 66] = rbv[i].x;
        db[(i * 16 + 1) * 66] = rbv[i].y;
        db[(i * 16 + 2) * 66] = rbv[i].z;
        db[(i * 16 + 3) * 66] = rbv[i].w;
      }
    }
    __syncthreads();
    if (c < 1) { G2_LOADA(1); G2_LOADB(1); }
    for (int k4o = 0; k4o < 16; ++k4o) {
      const int abase = (k4o * 4) * 16 + ((wv ^ (k4o & 3)) << 2);
#pragma unroll
      for (int u = 0; u < 4; ++u) {
        const int kk = k4o * 4 + u;
        const float b = sB[kk * 66 + lane];
        const float4 a = ld4(sA + abase + u * 16);
        acc[0] = fmaf(a.x, b, acc[0]); acc[1] = fmaf(a.y, b, acc[1]);
        acc[2] = fmaf(a.z, b, acc[2]); acc[3] = fmaf(a.w, b, acc[3]);
      }
    }
  }
#undef G2_LOADA
#undef G2_LOADB
#pragma unroll
  for (int i = 0; i < 4; ++i)
    P5[(size_t)kq * NB_DD + (size_t)(m0 + wv * 4 + i) * DDIM + j0 + lane] = acc[i];
}

// ---------------------------------------------------------------------------
// k_upd: Hn = (1-zv)*H + zv*tanh(fac*(sv5-hw5)+b5w+SumP5+b5u), zv likewise.
// grid 512 = 32 mb(8 rows) x 16 jb(32 cols); sv3/sv5 from psum in LDS.
// ---------------------------------------------------------------------------
__global__ void __launch_bounds__(256) k_upd(
    const float* __restrict__ Hc, const float* __restrict__ hwP,
    const float* __restrict__ psumP, const float* __restrict__ P5,
    const float* __restrict__ mat, const float* __restrict__ b3w,
    const float* __restrict__ b5w, const float* __restrict__ b5u,
    float* __restrict__ Hn) {
  __shared__ float s3[32], s5[32];
  const int t = threadIdx.x;
  const int m0 = (blockIdx.x >> 4) * 8;
  const int j0 = (blockIdx.x & 15) * 32;
  const float fac = mat[0] * (float)CNUM;
  if (t < 32) {
    const int j = j0 + t;
    float a = 0.f, b = 0.f;
#pragma unroll
    for (int mt = 0; mt < 8; ++mt) {
      a += psumP[mt * 512 + j] + psumP[3 * 4096 + mt * 512 + j];
      b += psumP[2 * 4096 + mt * 512 + j] + psumP[5 * 4096 + mt * 512 + j];
    }
    s3[t] = a; s5[t] = b;
  }
  __syncthreads();
  const int r = t >> 5, c = t & 31;
  const int m = m0 + r, j = j0 + c;
  const int idx = m * DDIM + j;
  const float hw3 = hwP[idx] + hwP[(size_t)4 * NB_DD + idx];
  const float hw5 = hwP[(size_t)2 * NB_DD + idx] + hwP[(size_t)6 * NB_DD + idx];
  const float hu3 = hwP[(size_t)3 * NB_DD + idx] + hwP[(size_t)7 * NB_DD + idx];
  const float p5 = P5[idx] + P5[(size_t)NB_DD + idx] +
                   P5[(size_t)2 * NB_DD + idx] + P5[(size_t)3 * NB_DD + idx];
  const float zv = sigf(fac * (s3[c] - hw3) + b3w[j] + hu3);
  const float hv = tanhf_(fac * (s5[c] - hw5) + b5w[j] + p5 + b5u[j]);
  Hn[idx] = (1.f - zv) * Hc[idx] + zv * hv;
}

// ---------------------------------------------------------------------------
// k_out (split-K=4 at the [H|X] concat + halves): Po[p] partials of
// [H|X]*wo^T. Tile 16m x 64j x 256k; grid 512 = 8jb x 4p x 16mb; XCD pinned.
// ---------------------------------------------------------------------------
__global__ void __launch_bounds__(256) k_out(const float* __restrict__ H,
                                             const float* __restrict__ X,
                                             const float* __restrict__ wo,
                                             float* __restrict__ Po) {
  __shared__ float sA[64 * 16];
  __shared__ float sB[64 * 66];
  const int t = threadIdx.x;
  const int bx = blockIdx.x;
  const int xcd = bx & 7, slot = bx >> 3;
  const int pp = xcd * 4 + (slot >> 4);
  const int mb = slot & 15;
  const int jb = pp >> 2, p = pp & 3;
  const int s = p >> 1, ksh = p & 1;
  const int m0 = mb * 16, j0 = jb * 64, kb = ksh * 256;
  const float* A = s ? X : H;
  const int lane = t & 63, wv = t >> 6;
  const int m = t >> 4, k4 = (t & 15) * 4;
  const int jr = t >> 2, kf = (t & 3) * 4;
  float4 rav, rbv[4];
  float acc[4] = {0.f, 0.f, 0.f, 0.f};

#define KO_LOAD(c)                                                              \
  {                                                                             \
    rav = ld4(A + (size_t)(m0 + m) * DDIM + kb + (c) * 64 + k4);                \
    const float* bp = wo + (size_t)(j0 + jr) * 1024 + s * 512 + kb + (c) * 64 + kf; \
    rbv[0] = ld4(bp);      rbv[1] = ld4(bp + 16);                               \
    rbv[2] = ld4(bp + 32); rbv[3] = ld4(bp + 48);                               \
  }

  KO_LOAD(0);
  for (int c = 0; c < 4; ++c) {
    __syncthreads();
    {
      float* da = sA + k4 * 16 + (m ^ ((t & 3) << 2));
      da[0] = rav.x; da[16] = rav.y; da[32] = rav.z; da[48] = rav.w;
      float* db = sB + kf * 66 + jr;
#pragma unroll
      for (int i = 0; i < 4; ++i) {
        db[(i * 16 + 0) * 66] = rbv[i].x;
        db[(i * 16 + 1) * 66] = rbv[i].y;
        db[(i * 16 + 2) * 66] = rbv[i].z;
        db[(i * 16 + 3) * 66] = rbv[i].w;
      }
    }
    __syncthreads();
    if (c < 3) KO_LOAD(c + 1);
    for (int k4o = 0; k4o < 16; ++k4o) {
      const int abase = (k4o * 4) * 16 + ((wv ^ (k4o & 3)) << 2);
#pragma unroll
      for (int u = 0; u < 4; ++u) {
        const int kk = k4o * 4 + u;
        const float b = sB[kk * 66 + lane];
        const float4 a = ld4(sA + abase + u * 16);
        acc[0] = fmaf(a.x, b, acc[0]); acc[1] = fmaf(a.y, b, acc[1]);
        acc[2] = fmaf(a.z, b, acc[2]); acc[3] = fmaf(a.w, b, acc[3]);
      }
    }
  }
#undef KO_LOAD
#pragma unroll
  for (int i = 0; i < 4; ++i)
    Po[(size_t)p * NB_DD + (size_t)(m0 + wv * 4 + i) * DDIM + j0 + lane] = acc[i];
}

// ---------------------------------------------------------------------------
// k_obj: out = relu(sum Po + bo) * Wcs^T + bc. Tile 8m x 64j, grid (32,3).
// A (relu'd activations, 8x512) staged once; B per 64-chunk.
// ---------------------------------------------------------------------------
__global__ void __launch_bounds__(256) k_obj(const float* __restrict__ Po,
                                             const float* __restrict__ bo,
                                             const float* __restrict__ Wcs,
                                             const float* __restrict__ bc,
                                             float* __restrict__ out) {
  __shared__ float sAo[8 * 519];
  __shared__ float sB[64 * 66];
  const int t = threadIdx.x;
  const int m0 = blockIdx.x * 8, j0 = blockIdx.y * 64;
  const int lane = t & 63, wv = t >> 6;
  const int jr = t >> 2, kf = (t & 3) * 4;
  const int co = j0 + jr;
  {  // stage relu(sum Po + bo) for 8 rows x 512 k
    const int m = t >> 5, ks4 = (t & 31) * 4;
#pragma unroll
    for (int kb2 = 0; kb2 < 4; ++kb2) {
      const int k = kb2 * 128 + ks4;
      const int idx = (m0 + m) * DDIM + k;
      const float4 p0 = ld4(Po + idx);
      const float4 p1 = ld4(Po + (size_t)NB_DD + idx);
      const float4 p2 = ld4(Po + (size_t)2 * NB_DD + idx);
      const float4 p3 = ld4(Po + (size_t)3 * NB_DD + idx);
      const float4 bb = ld4(bo + k);
      float* da = sAo + m * 519 + k;
      da[0] = fmaxf(p0.x + p1.x + p2.x + p3.x + bb.x, 0.f);
      da[1] = fmaxf(p0.y + p1.y + p2.y + p3.y + bb.y, 0.f);
      da[2] = fmaxf(p0.z + p1.z + p2.z + p3.z + bb.z, 0.f);
      da[3] = fmaxf(p0.w + p1.w + p2.w + p3.w + bb.w, 0.f);
    }
  }
  float4 rbv[4];
  float acc[2] = {0.f, 0.f};
#define OB_LOADB(c)                                                         \
  {                                                                         \
    if (co < CNUM) {                                                        \
      const float* bp = Wcs + (size_t)co * DDIM + (c) * 64 + kf;            \
      rbv[0] = ld4(bp);      rbv[1] = ld4(bp + 16);                         \
      rbv[2] = ld4(bp + 32); rbv[3] = ld4(bp + 48);                         \
    } else {                                                                \
      rbv[0] = rbv[1] = rbv[2] = rbv[3] = make_float4(0.f, 0.f, 0.f, 0.f);  \
    }                                                                       \
  }
  OB_LOADB(0);
  for (int c = 0; c < 8; ++c) {
    __syncthreads();
    {
      float* db = sB + kf * 66 + jr;
#pragma unroll
      for (int i = 0; i < 4; ++i) {
        db[(i * 16 + 0) * 66] = rbv[i].x;
        db[(i * 16 + 1) * 66] = rbv[i].y;
        db[(i * 16 + 2) * 66] = rbv[i].z;
        db[(i * 16 + 3) * 66] = rbv[i].w;
      }
    }
    __syncthreads();
    if (c < 7) OB_LOADB(c + 1);
    const float* a0p = sAo + (wv * 2) * 519 + c * 64;
    const float* a1p = a0p + 519;
#pragma unroll 16
    for (int kk = 0; kk < 64; ++kk) {
      const float b = sB[kk * 66 + lane];
      acc[0] = fmaf(a0p[kk], b, acc[0]);
      acc[1] = fmaf(a1p[kk], b, acc[1]);
    }
  }
#undef OB_LOADB
  const int c_ = j0 + lane;
  if (c_ < CNUM) {
    const float bcv = bc[c_];
    out[(m0 + wv * 2 + 0) * CNUM + c_] = acc[0] + bcv;
    out[(m0 + wv * 2 + 1) * CNUM + c_] = acc[1] + bcv;
  }
}

extern "C" void kernel_launch(void* const* d_in, const int* in_sizes, int n_in,
                              void* d_out, int out_size, void* d_ws, size_t ws_size,
                              hipStream_t stream) {
  const float* X = (const float*)d_in[0];
  const float* mat = (const float*)d_in[1];
  const float* w3w = (const float*)d_in[2];
  const float* b3w = (const float*)d_in[3];
  const float* w3u = (const float*)d_in[4];
  const float* b3u = (const float*)d_in[5];
  const float* w4w = (const float*)d_in[6];
  const float* b4w = (const float*)d_in[7];
  // d_in[8], d_in[9] (w4u, b4u) unused — reference reuses w3u/b3u (faithful bug)
  const float* w5w = (const float*)d_in[10];
  const float* b5w = (const float*)d_in[11];
  const float* w5u = (const float*)d_in[12];
  const float* b5u = (const float*)d_in[13];
  const float* wo = (const float*)d_in[14];
  const float* bo = (const float*)d_in[15];
  const float* wc = (const float*)d_in[16];
  const float* bc = (const float*)d_in[17];
  float* out = (float*)d_out;
  float* ws = (float*)d_ws;

  // workspace (floats): ~9.8 MB
  float* Wcs = ws;                    // 151*512          = 77312
  float* hwP = Wcs + 77312;           // 2kh*4z*256*512   = 1048576
  float* psumP = hwP + 1048576;       // 2kh*3z*8mb*512   = 24576
  float* P5 = psumP + 24576;          // 4kq*256*512      = 524288
  float* Po = P5 + 524288;            // 4p*256*512       = 524288
  float* H0 = Po + 524288;            // 131072
  float* H1 = H0 + 131072;            // 131072

  // iter 1 (Hc = X): G1 with Wcs tail blocks (memory-bound, co-scheduled)
  k_G1<<<NG1 + CNUM * 4, 256, 0, stream>>>(X, w3w, w4w, w5w, w3u, b3u, hwP, psumP, wc, Wcs);
  k_G2<<<512, 256, 0, stream>>>(X, hwP, psumP, mat, b4w, w5u, P5);
  k_upd<<<512, 256, 0, stream>>>(X, hwP, psumP, P5, mat, b3w, b5w, b5u, H0);
  // iter 2
  k_G1<<<NG1, 256, 0, stream>>>(H0, w3w, w4w, w5w, w3u, b3u, hwP, psumP, wc, Wcs);
  k_G2<<<512, 256, 0, stream>>>(H0, hwP, psumP, mat, b4w, w5u, P5);
  k_upd<<<512, 256, 0, stream>>>(H0, hwP, psumP, P5, mat, b3w, b5w, b5u, H1);
  // iter 3
  k_G1<<<NG1, 256, 0, stream>>>(H1, w3w, w4w, w5w, w3u, b3u, hwP, psumP, wc, Wcs);
  k_G2<<<512, 256, 0, stream>>>(H1, hwP, psumP, mat, b4w, w5u, P5);
  k_upd<<<512, 256, 0, stream>>>(H1, hwP, psumP, P5, mat, b3w, b5w, b5u, H0);
  // epilogue
  k_out<<<512, 256, 0, stream>>>(H0, X, wo, Po);
  k_obj<<<dim3(32, 3), 256, 0, stream>>>(Po, bo, Wcs, bc, out);
}